// Round 9
// baseline (280.575 us; speedup 1.0000x reference)
//
#include <hip/hip_runtime.h>
#include <hip/hip_bf16.h>
#include <cstddef>
#include <cstdint>

#define T_TOK 4096
#define H_DIM 2048
#define E_NUM 8
#define I_DIM 1024
#define TWO_I 2048
#define MROWS 5120      // worst-case 128-padded slot rows
#define MT    40        // MROWS/128 M-tiles

typedef __attribute__((ext_vector_type(8))) short bf16x8;
typedef __attribute__((ext_vector_type(4))) float f32x4;
typedef __attribute__((ext_vector_type(4))) int   i32x4;

// -------- workspace layout (bytes); ws >= 128 MiB proven --------
#define WS_SCALE   0            // f32[4096]
#define WS_COUNTS  16384        // int[8]
#define WS_BUCKETS 16512        // int[8*4096]  ends 147584
#define WS_SLOTTOK 147584       // int[5120]    ends 168064
#define WS_XSG     (1u<<20)     // bf16[5120*2048] = 20.97 MB
#define WS_ACT     (23u<<20)    // bf16[5120*1024] = 10.49 MB

__device__ __forceinline__ short f2bf(float f) {
    uint32_t u = __builtin_bit_cast(uint32_t, f);
    u += 0x7fffu + ((u >> 16) & 1u);
    return (short)(u >> 16);
}

__device__ __forceinline__ void gload16(const void* g, void* l) {
    __builtin_amdgcn_global_load_lds(
        (const __attribute__((address_space(1))) void*)g,
        (__attribute__((address_space(3))) void*)l, 16, 0, 0);
}

// pack bf16(lo)|bf16(hi)<<16 in one instruction (no builtin on gfx950)
__device__ __forceinline__ uint32_t cvt_pk_bf16(float lo, float hi) {
    uint32_t r;
    asm("v_cvt_pk_bf16_f32 %0, %1, %2" : "=v"(r) : "v"(lo), "v"(hi));
    return r;
}

// ---------------- router (vectorized float4, wave per token) ----------------
__global__ __launch_bounds__(256) void router_kernel(
    const float* __restrict__ x, const float* __restrict__ gw,
    float* __restrict__ scale, int* __restrict__ counts, int* __restrict__ buckets)
{
    const int wid  = threadIdx.x >> 6;
    const int lane = threadIdx.x & 63;
    const int t = blockIdx.x * 4 + wid;
    if (t >= T_TOK) return;

    float4 a4[E_NUM];
#pragma unroll
    for (int e = 0; e < E_NUM; ++e) a4[e] = make_float4(0.f, 0.f, 0.f, 0.f);

    const float4* xr  = (const float4*)(x + (size_t)t * H_DIM);
    const float4* gwv = (const float4*)gw;
#pragma unroll
    for (int it = 0; it < 8; ++it) {
        const int idx = lane + it * 64;
        float4 xv = xr[idx];
#pragma unroll
        for (int e = 0; e < E_NUM; ++e) {
            float4 wv = gwv[e * 512 + idx];
            a4[e].x = fmaf(xv.x, wv.x, a4[e].x);
            a4[e].y = fmaf(xv.y, wv.y, a4[e].y);
            a4[e].z = fmaf(xv.z, wv.z, a4[e].z);
            a4[e].w = fmaf(xv.w, wv.w, a4[e].w);
        }
    }
    float acc[E_NUM];
#pragma unroll
    for (int e = 0; e < E_NUM; ++e) {
        float v = (a4[e].x + a4[e].y) + (a4[e].z + a4[e].w);
#pragma unroll
        for (int off = 32; off > 0; off >>= 1) v += __shfl_xor(v, off);
        acc[e] = v;
    }
    if (lane == 0) {
        int best = 0; float bv = acc[0];
#pragma unroll
        for (int e = 1; e < E_NUM; ++e) { if (acc[e] > bv) { bv = acc[e]; best = e; } }
        scale[t] = 1.f / (1.f + expf(-bv));
        int pos = atomicAdd(&counts[best], 1);
        buckets[best * T_TOK + pos] = t;
    }
}

// ---------------- gather: xsg[slot] = bf16(scale[tok] * x[tok]) --------------
// (128-padded prefix computed inline from counts; no offs kernel)
__global__ __launch_bounds__(256) void gather_kernel(
    const float* __restrict__ x, const float* __restrict__ scale,
    const int* __restrict__ counts, const int* __restrict__ buckets,
    short* __restrict__ xsg, int* __restrict__ slot_tok)
{
    const int r = blockIdx.x;          // slot row 0..5119
    int run = 0, eSel = 0, pos = 0;
    bool valid = false;
#pragma unroll
    for (int k = 0; k < E_NUM; ++k) {
        const int c  = counts[k];
        const int cp = (c + 127) & ~127;
        if (r >= run && r < run + cp) { eSel = k; pos = r - run; valid = (pos < c); }
        run += cp;
    }
    const int tok = valid ? buckets[eSel * T_TOK + pos] : -1;
    if (threadIdx.x == 0) slot_tok[r] = tok;

    short* orow = xsg + (size_t)r * H_DIM + threadIdx.x * 8;
    if (!valid) {
        i32x4 z = {0, 0, 0, 0};
        *(i32x4*)orow = z;
        return;
    }
    const float sc = scale[tok];
    const float* xr = x + (size_t)tok * H_DIM + threadIdx.x * 8;
    float4 a = *(const float4*)xr;
    float4 b = *(const float4*)(xr + 4);
    short o[8] __attribute__((aligned(16)));
    o[0] = f2bf(a.x * sc); o[1] = f2bf(a.y * sc);
    o[2] = f2bf(a.z * sc); o[3] = f2bf(a.w * sc);
    o[4] = f2bf(b.x * sc); o[5] = f2bf(b.y * sc);
    o[6] = f2bf(b.z * sc); o[7] = f2bf(b.w * sc);
    *(i32x4*)orow = *(const i32x4*)o;
}

// ================== grouped MFMA GEMMs, fused B transpose+cvt ===============
// 128x128 tile, 4 waves, BK=32, dbuf LDS 32KB, single barrier per K-step.
// A: bf16 rows staged via global_load_lds (unchanged r8 path).
// B: f32 weights in native [k][n] layout -> per-thread reg load (4x float4),
//    v_cvt_pk_bf16_f32, ds_write_b32 into the same [rb][32k] bf16 LDS layout
//    the MFMA fragments read. Write pattern = 4-way bank conflict (free-ish).

#define CMP_BODY(BUF)                                                          \
  {                                                                            \
    const short* pA = &sA[BUF][offA];                                          \
    const short* pB = &sB[BUF][offB];                                          \
    bf16x8 a0 = *(const bf16x8*)pA;                                            \
    bf16x8 a1 = *(const bf16x8*)(pA + 512);                                    \
    _Pragma("unroll") for (int nf = 0; nf < 8; ++nf) {                         \
        bf16x8 b = *(const bf16x8*)(pB + nf * 512);                            \
        acc[0][nf] = __builtin_amdgcn_mfma_f32_16x16x32_bf16(a0, b,            \
                         acc[0][nf], 0, 0, 0);                                 \
        acc[1][nf] = __builtin_amdgcn_mfma_f32_16x16x32_bf16(a1, b,            \
                         acc[1][nf], 0, 0, 0);                                 \
    }                                                                          \
  }

__global__ __launch_bounds__(256) void gemm1_mfma_kernel(
    const short* __restrict__ xsg, const float* __restrict__ gup,
    const int* __restrict__ counts, short* __restrict__ act)
{
    __shared__ short sA[2][128 * 32];
    __shared__ short sB[2][128 * 32];

    const int bid = blockIdx.x;
    const int wg  = (bid & 7) * 80 + (bid >> 3);   // bijective: 640 % 8 == 0
    const int nt  = wg / MT;
    const int mt  = wg - nt * MT;
    const int m0  = mt << 7;
    const int f0  = nt << 6;

    int run = 0, e = 0;
#pragma unroll
    for (int k = 0; k < E_NUM; ++k) {
        if (m0 >= run) e = k;
        run += (counts[k] + 127) & ~127;
    }
    if (m0 >= run) return;

    const int tid = threadIdx.x, lane = tid & 63, w = tid >> 6;
    const int g = lane & 3, lr = lane >> 2;
    const int rA0 = (2 * w) * 16 + lr, rA1 = rA0 + 16;

    const short* srcA0 = xsg + (size_t)(m0 + rA0) * H_DIM + g * 8;
    const short* srcA1 = xsg + (size_t)(m0 + rA1) * H_DIM + g * 8;

    // B staging geometry: thread -> k-pair kp, col-quad rq
    const int kp = (tid & 15) * 2;       // 0..30 (even)
    const int rq = (tid >> 4) & 15;      // 0..15
    const float* gB  = gup + (size_t)e * H_DIM * TWO_I;
    const float* pB0 = gB + (size_t)kp * TWO_I + (f0 + rq * 4);          // up
    const float* pB1 = gB + (size_t)kp * TWO_I + (I_DIM + f0 + rq * 4);  // gate
    const int rb0 = rq * 4, rb1 = 64 + rq * 4;

    const int lm = lane & 15, lg8 = (lane >> 4) * 8;
    const int offA = (w * 32 + lm) * 32 + lg8;
    const int offB = lm * 32 + lg8;

    f32x4 acc[2][8];
#pragma unroll
    for (int i = 0; i < 2; ++i)
#pragma unroll
        for (int j = 0; j < 8; ++j) acc[i][j] = (f32x4){0.f, 0.f, 0.f, 0.f};

    float4 bu0, bu1, bg0, bg1;
    auto STG_A = [&](int buf, int kb) {
        gload16(srcA0 + kb, &sA[buf][(2 * w) * 512]);
        gload16(srcA1 + kb, &sA[buf][(2 * w + 1) * 512]);
    };
    auto LOAD_B = [&](int kb) {
        const float* r0 = pB0 + (size_t)kb * TWO_I;
        bu0 = *(const float4*)r0;
        bu1 = *(const float4*)(r0 + TWO_I);
        const float* r1 = pB1 + (size_t)kb * TWO_I;
        bg0 = *(const float4*)r1;
        bg1 = *(const float4*)(r1 + TWO_I);
    };
    auto WRITE_B = [&](int buf) {
        const float* u0 = (const float*)&bu0; const float* u1 = (const float*)&bu1;
        const float* g0 = (const float*)&bg0; const float* g1 = (const float*)&bg1;
#pragma unroll
        for (int i = 0; i < 4; ++i) {
            *(uint32_t*)&sB[buf][(rb0 + i) * 32 + kp] = cvt_pk_bf16(u0[i], u1[i]);
            *(uint32_t*)&sB[buf][(rb1 + i) * 32 + kp] = cvt_pk_bf16(g0[i], g1[i]);
        }
    };

    // prologue: tile 0 staged
    STG_A(0, 0);
    LOAD_B(0);
    WRITE_B(0);

    const int NKT = H_DIM / 32;   // 64
    int cur = 0;
    for (int t = 0; t < NKT; ++t) {
        __syncthreads();          // drains vmcnt/lgkm: tile t fully in LDS
        if (t + 1 < NKT) {
            STG_A(cur ^ 1, (t + 1) * 32);
            LOAD_B((t + 1) * 32);
        }
        CMP_BODY(cur);
        if (t + 1 < NKT) WRITE_B(cur ^ 1);   // after CMP: HBM latency hidden
        cur ^= 1;
    }

    // epilogue: act[slot] = up * gate * sigmoid(gate)
    const int rbase = w * 32 + (lane >> 4) * 4;
#pragma unroll
    for (int mi = 0; mi < 2; ++mi) {
#pragma unroll
        for (int rr = 0; rr < 4; ++rr) {
            const int row = rbase + mi * 16 + rr;
            short* orow = act + (size_t)(m0 + row) * I_DIM + f0 + lm;
#pragma unroll
            for (int nf = 0; nf < 4; ++nf) {
                float up = acc[mi][nf][rr];
                float gt = acc[mi][nf + 4][rr];
                float v  = up * gt / (1.f + expf(-gt));
                orow[nf * 16] = f2bf(v);
            }
        }
    }
}

__global__ __launch_bounds__(256) void gemm2_mfma_kernel(
    const short* __restrict__ actm, const float* __restrict__ dw,
    const int* __restrict__ counts, const int* __restrict__ slot_tok,
    float* __restrict__ out)
{
    __shared__ short sA[2][128 * 32];
    __shared__ short sB[2][128 * 32];
    __shared__ int   sTok[128];

    const int bid = blockIdx.x;
    const int wg  = (bid & 7) * 80 + (bid >> 3);
    const int nt  = wg / MT;
    const int mt  = wg - nt * MT;
    const int m0  = mt << 7;
    const int h0  = nt << 7;

    int run = 0, e = 0;
#pragma unroll
    for (int k = 0; k < E_NUM; ++k) {
        if (m0 >= run) e = k;
        run += (counts[k] + 127) & ~127;
    }
    if (m0 >= run) return;

    const int tid = threadIdx.x, lane = tid & 63, w = tid >> 6;
    if (tid < 128) sTok[tid] = slot_tok[m0 + tid];

    const int g = lane & 3, lr = lane >> 2;
    const int rA0 = (2 * w) * 16 + lr, rA1 = rA0 + 16;

    const short* srcA0 = actm + (size_t)(m0 + rA0) * I_DIM + g * 8;
    const short* srcA1 = actm + (size_t)(m0 + rA1) * I_DIM + g * 8;

    const int kp = (tid & 15) * 2;
    const int rq = (tid >> 4) & 15;
    const float* gB  = dw + (size_t)e * I_DIM * H_DIM;
    const float* pB0 = gB + (size_t)kp * H_DIM + (h0 + rq * 4);
    const float* pB1 = pB0 + 64;
    const int rb0 = rq * 4, rb1 = 64 + rq * 4;

    const int lm = lane & 15, lg8 = (lane >> 4) * 8;
    const int offA = (w * 32 + lm) * 32 + lg8;
    const int offB = lm * 32 + lg8;

    f32x4 acc[2][8];
#pragma unroll
    for (int i = 0; i < 2; ++i)
#pragma unroll
        for (int j = 0; j < 8; ++j) acc[i][j] = (f32x4){0.f, 0.f, 0.f, 0.f};

    float4 bu0, bu1, bg0, bg1;
    auto STG_A = [&](int buf, int kb) {
        gload16(srcA0 + kb, &sA[buf][(2 * w) * 512]);
        gload16(srcA1 + kb, &sA[buf][(2 * w + 1) * 512]);
    };
    auto LOAD_B = [&](int kb) {
        const float* r0 = pB0 + (size_t)kb * H_DIM;
        bu0 = *(const float4*)r0;
        bu1 = *(const float4*)(r0 + H_DIM);
        const float* r1 = pB1 + (size_t)kb * H_DIM;
        bg0 = *(const float4*)r1;
        bg1 = *(const float4*)(r1 + H_DIM);
    };
    auto WRITE_B = [&](int buf) {
        const float* u0 = (const float*)&bu0; const float* u1 = (const float*)&bu1;
        const float* g0 = (const float*)&bg0; const float* g1 = (const float*)&bg1;
#pragma unroll
        for (int i = 0; i < 4; ++i) {
            *(uint32_t*)&sB[buf][(rb0 + i) * 32 + kp] = cvt_pk_bf16(u0[i], u1[i]);
            *(uint32_t*)&sB[buf][(rb1 + i) * 32 + kp] = cvt_pk_bf16(g0[i], g1[i]);
        }
    };

    STG_A(0, 0);
    LOAD_B(0);
    WRITE_B(0);

    const int NKT = I_DIM / 32;   // 32
    int cur = 0;
    for (int t = 0; t < NKT; ++t) {
        __syncthreads();
        if (t + 1 < NKT) {
            STG_A(cur ^ 1, (t + 1) * 32);
            LOAD_B((t + 1) * 32);
        }
        CMP_BODY(cur);
        if (t + 1 < NKT) WRITE_B(cur ^ 1);
        cur ^= 1;
    }

    const int rbase = w * 32 + (lane >> 4) * 4;
#pragma unroll
    for (int mi = 0; mi < 2; ++mi) {
#pragma unroll
        for (int rr = 0; rr < 4; ++rr) {
            const int row = rbase + mi * 16 + rr;
            const int tok = sTok[row];
            if (tok < 0) continue;
            float* orow = out + (size_t)tok * H_DIM + h0 + lm;
#pragma unroll
            for (int nf = 0; nf < 8; ++nf) orow[nf * 16] = acc[mi][nf][rr];
        }
    }
}

extern "C" void kernel_launch(void* const* d_in, const int* in_sizes, int n_in,
                              void* d_out, int out_size, void* d_ws, size_t ws_size,
                              hipStream_t stream) {
    const float* x   = (const float*)d_in[0];
    const float* gw  = (const float*)d_in[1];
    const float* gup = (const float*)d_in[2];
    const float* dw  = (const float*)d_in[3];
    float* out = (float*)d_out;

    char* ws = (char*)d_ws;
    float* scale    = (float*)(ws + WS_SCALE);
    int*   counts   = (int*)(ws + WS_COUNTS);
    int*   buckets  = (int*)(ws + WS_BUCKETS);
    int*   slot_tok = (int*)(ws + WS_SLOTTOK);
    short* xsg      = (short*)(ws + WS_XSG);
    short* act      = (short*)(ws + WS_ACT);

    hipMemsetAsync(counts, 0, E_NUM * sizeof(int), stream);
    router_kernel<<<T_TOK / 4, 256, 0, stream>>>(x, gw, scale, counts, buckets);
    gather_kernel<<<MROWS, 256, 0, stream>>>(x, scale, counts, buckets, xsg, slot_tok);

    gemm1_mfma_kernel<<<MT * 16, 256, 0, stream>>>(xsg, gup, counts, act);
    gemm2_mfma_kernel<<<MT * 16, 256, 0, stream>>>(act, dw, counts, slot_tok, out);
}

// Round 10
// 238.395 us; speedup vs baseline: 1.1769x; 1.1769x over previous
//
#include <hip/hip_runtime.h>
#include <hip/hip_bf16.h>
#include <cstddef>
#include <cstdint>

#define T_TOK 4096
#define H_DIM 2048
#define E_NUM 8
#define I_DIM 1024
#define TWO_I 2048
#define MROWS 5120      // worst-case 128-padded slot rows
#define MT    40        // MROWS/128 M-tiles

typedef __attribute__((ext_vector_type(8))) short bf16x8;
typedef __attribute__((ext_vector_type(4))) float f32x4;
typedef __attribute__((ext_vector_type(4))) int   i32x4;

// -------- workspace layout (bytes); ws >= 134217728 proven --------
#define WS_SCALE   0               // f32[4096]
#define WS_COUNTS  16384           // int[8]
#define WS_OFFP    16448           // int[9]
#define WS_BUCKETS 16512           // int[8*4096]  ends 147584
#define WS_SLOTTOK 147584          // int[5120]    ends 168064
#define WS_XSG     (1u<<20)        // bf16[5120*2048] ends 22020096
#define WS_ACT     22020096u       // bf16[5120*1024] ends 32505856
#define WS_W1T     32505856u       // bf16[8][2048][2048] ends 99614720
#define WS_W2T     99614720u       // bf16[8][2048][1024] ends 133169152 (<134217728)

__device__ __forceinline__ short f2bf(float f) {
    uint32_t u = __builtin_bit_cast(uint32_t, f);
    u += 0x7fffu + ((u >> 16) & 1u);
    return (short)(u >> 16);
}

__device__ __forceinline__ void gload16(const void* g, void* l) {
    __builtin_amdgcn_global_load_lds(
        (const __attribute__((address_space(1))) void*)g,
        (__attribute__((address_space(3))) void*)l, 16, 0, 0);
}

// ---------------- prep kernel: router + both weight transposes fused --------
// blocks [0,1024): router (4 tokens/block, wave per token)
// blocks [1024,9216): transpose gup -> w1t (K=2048, N=2048)
// blocks [9216,13312): transpose dw  -> w2t (K=1024, N=2048)
__device__ __forceinline__ void router_body(
    int blk, const float* __restrict__ x, const float* __restrict__ gw,
    float* __restrict__ scale, int* __restrict__ counts, int* __restrict__ buckets)
{
    const int wid  = threadIdx.x >> 6;
    const int lane = threadIdx.x & 63;
    const int t = blk * 4 + wid;
    if (t >= T_TOK) return;

    float4 a4[E_NUM];
#pragma unroll
    for (int e = 0; e < E_NUM; ++e) a4[e] = make_float4(0.f, 0.f, 0.f, 0.f);

    const float4* xr  = (const float4*)(x + (size_t)t * H_DIM);
    const float4* gwv = (const float4*)gw;
#pragma unroll
    for (int it = 0; it < 8; ++it) {
        const int idx = lane + it * 64;
        float4 xv = xr[idx];
#pragma unroll
        for (int e = 0; e < E_NUM; ++e) {
            float4 wv = gwv[e * 512 + idx];
            a4[e].x = fmaf(xv.x, wv.x, a4[e].x);
            a4[e].y = fmaf(xv.y, wv.y, a4[e].y);
            a4[e].z = fmaf(xv.z, wv.z, a4[e].z);
            a4[e].w = fmaf(xv.w, wv.w, a4[e].w);
        }
    }
    float acc[E_NUM];
#pragma unroll
    for (int e = 0; e < E_NUM; ++e) {
        float v = (a4[e].x + a4[e].y) + (a4[e].z + a4[e].w);
#pragma unroll
        for (int off = 32; off > 0; off >>= 1) v += __shfl_xor(v, off);
        acc[e] = v;
    }
    if (lane == 0) {
        int best = 0; float bv = acc[0];
#pragma unroll
        for (int e = 1; e < E_NUM; ++e) { if (acc[e] > bv) { bv = acc[e]; best = e; } }
        scale[t] = 1.f / (1.f + expf(-bv));
        int pos = atomicAdd(&counts[best], 1);
        buckets[best * T_TOK + pos] = t;
    }
}

__global__ __launch_bounds__(256) void prep_kernel(
    const float* __restrict__ x, const float* __restrict__ gw,
    const float* __restrict__ gup, const float* __restrict__ dw,
    float* __restrict__ scale, int* __restrict__ counts,
    int* __restrict__ buckets, short* __restrict__ w1t, short* __restrict__ w2t)
{
    __shared__ float s[64][65];
    const int b = blockIdx.x;
    if (b < 1024) { router_body(b, x, gw, scale, counts, buckets); return; }

    const float* src; short* dst; int K, e, k0, n0;
    if (b < 1024 + 8192) {
        const int idx = b - 1024;            // T1: gup [e][2048][2048]
        src = gup; dst = w1t; K = H_DIM;
        e  = idx >> 10;
        k0 = (idx & 31) * 64;
        n0 = ((idx >> 5) & 31) * 64;
    } else {
        const int idx = b - 9216;            // T2: dw [e][1024][2048]
        src = dw; dst = w2t; K = I_DIM;
        e  = idx >> 9;
        k0 = (idx & 15) * 64;
        n0 = ((idx >> 4) & 31) * 64;
    }
    const int N = TWO_I;
    const int t = threadIdx.x;

    const float* S = src + ((size_t)e * K + k0) * N + n0;
    const int kr = t >> 4, nc = (t & 15) * 4;
#pragma unroll
    for (int i = 0; i < 4; ++i) {
        float4 v = *(const float4*)(S + (size_t)(kr + i * 16) * N + nc);
        s[kr + i * 16][nc + 0] = v.x;
        s[kr + i * 16][nc + 1] = v.y;
        s[kr + i * 16][nc + 2] = v.z;
        s[kr + i * 16][nc + 3] = v.w;
    }
    __syncthreads();

    const int nr = t >> 2, kc = (t & 3) * 16;
    short tmp[16] __attribute__((aligned(16)));
#pragma unroll
    for (int j = 0; j < 16; ++j) tmp[j] = f2bf(s[kc + j][nr]);
    short* D = dst + ((size_t)e * N + n0 + nr) * K + k0 + kc;
    *(i32x4*)D       = *(const i32x4*)tmp;
    *(i32x4*)(D + 8) = *(const i32x4*)(tmp + 8);
}

// ---------------- 128-padded prefix offsets ----------------
__global__ void offs_kernel(const int* __restrict__ counts, int* __restrict__ offP) {
    if (threadIdx.x == 0) {
        int run = 0;
#pragma unroll
        for (int e = 0; e < E_NUM; ++e) { offP[e] = run; run += (counts[e] + 127) & ~127; }
        offP[E_NUM] = run;
    }
}

// ---------------- gather: xsg[slot] = bf16(scale[tok] * x[tok]) ----------------
__global__ __launch_bounds__(256) void gather_kernel(
    const float* __restrict__ x, const float* __restrict__ scale,
    const int* __restrict__ counts, const int* __restrict__ offP,
    const int* __restrict__ buckets, short* __restrict__ xsg,
    int* __restrict__ slot_tok)
{
    const int r = blockIdx.x;          // slot row 0..5119
    int e = 0;
#pragma unroll
    for (int k = 1; k < E_NUM; ++k) if (r >= offP[k]) e = k;
    const int pos = r - offP[e];
    const bool valid = (r < offP[E_NUM]) && (pos < counts[e]);
    const int tok = valid ? buckets[e * T_TOK + pos] : -1;
    if (threadIdx.x == 0) slot_tok[r] = tok;

    short* orow = xsg + (size_t)r * H_DIM + threadIdx.x * 8;
    if (!valid) {
        i32x4 z = {0, 0, 0, 0};
        *(i32x4*)orow = z;
        return;
    }
    const float sc = scale[tok];
    const float* xr = x + (size_t)tok * H_DIM + threadIdx.x * 8;
    float4 a = *(const float4*)xr;
    float4 b = *(const float4*)(xr + 4);
    short o[8] __attribute__((aligned(16)));
    o[0] = f2bf(a.x * sc); o[1] = f2bf(a.y * sc);
    o[2] = f2bf(a.z * sc); o[3] = f2bf(a.w * sc);
    o[4] = f2bf(b.x * sc); o[5] = f2bf(b.y * sc);
    o[6] = f2bf(b.z * sc); o[7] = f2bf(b.w * sc);
    *(i32x4*)orow = *(const i32x4*)o;
}

// ---------------- grouped MFMA GEMM1 + SwiGLU (r8-proven 128x128 2-phase) ----
__global__ __launch_bounds__(256) void gemm1_mfma_kernel(
    const short* __restrict__ xsg, const short* __restrict__ w1t,
    const int* __restrict__ offP, short* __restrict__ act)
{
    __shared__ short sA[2][128 * 32];
    __shared__ short sB[2][128 * 32];

    const int bid = blockIdx.x;
    const int wg  = (bid & 7) * 80 + (bid >> 3);   // bijective: 640 % 8 == 0
    const int nt  = wg / MT;
    const int mt  = wg - nt * MT;
    const int m0  = mt << 7;
    if (m0 >= offP[E_NUM]) return;
    const int f0  = nt << 6;

    int e = 0;
#pragma unroll
    for (int k = 1; k < E_NUM; ++k) if (m0 >= offP[k]) e = k;

    const int tid = threadIdx.x, lane = tid & 63, w = tid >> 6;
    const int g = lane & 3, lr = lane >> 2;
    const int rA0 = (2 * w) * 16 + lr, rA1 = rA0 + 16;

    const short* srcA0 = xsg + (size_t)(m0 + rA0) * H_DIM + g * 8;
    const short* srcA1 = xsg + (size_t)(m0 + rA1) * H_DIM + g * 8;
    const int n0r = (rA0 < 64) ? (f0 + rA0) : (I_DIM + f0 + (rA0 & 63));
    const int n1r = (rA1 < 64) ? (f0 + rA1) : (I_DIM + f0 + (rA1 & 63));
    const short* srcB0 = w1t + ((size_t)e * TWO_I + n0r) * H_DIM + g * 8;
    const short* srcB1 = w1t + ((size_t)e * TWO_I + n1r) * H_DIM + g * 8;

    const int lm = lane & 15, lg8 = (lane >> 4) * 8;
    const int offA = (w * 32 + lm) * 32 + lg8;   // + mi*512
    const int offB = lm * 32 + lg8;              // + nf*512

    f32x4 acc[2][8];
#pragma unroll
    for (int i = 0; i < 2; ++i)
#pragma unroll
        for (int j = 0; j < 8; ++j) acc[i][j] = (f32x4){0.f, 0.f, 0.f, 0.f};

    auto STG = [&](int buf, int kb) {
        gload16(srcA0 + kb, &sA[buf][(2 * w) * 512]);
        gload16(srcA1 + kb, &sA[buf][(2 * w + 1) * 512]);
        gload16(srcB0 + kb, &sB[buf][(2 * w) * 512]);
        gload16(srcB1 + kb, &sB[buf][(2 * w + 1) * 512]);
    };
    auto CMP = [&](int buf) {
        const short* pA = &sA[buf][offA];
        const short* pB = &sB[buf][offB];
        bf16x8 a0 = *(const bf16x8*)pA;
        bf16x8 a1 = *(const bf16x8*)(pA + 512);
#pragma unroll
        for (int nf = 0; nf < 8; ++nf) {
            bf16x8 b = *(const bf16x8*)(pB + nf * 512);
            acc[0][nf] = __builtin_amdgcn_mfma_f32_16x16x32_bf16(a0, b, acc[0][nf], 0, 0, 0);
            acc[1][nf] = __builtin_amdgcn_mfma_f32_16x16x32_bf16(a1, b, acc[1][nf], 0, 0, 0);
        }
    };

    int cur = 0;
    STG(0, 0);
    for (int kb = 32; kb < H_DIM; kb += 32) {
        __syncthreads();          // drains vmcnt: staged cur is complete
        STG(cur ^ 1, kb);         // prefetch next tile (overlaps compute)
        CMP(cur);
        cur ^= 1;
    }
    __syncthreads();
    CMP(cur);

    // epilogue: act[slot] = up * gate * sigmoid(gate)
    const int rbase = w * 32 + (lane >> 4) * 4;
#pragma unroll
    for (int mi = 0; mi < 2; ++mi) {
#pragma unroll
        for (int rr = 0; rr < 4; ++rr) {
            const int row = rbase + mi * 16 + rr;
            short* orow = act + (size_t)(m0 + row) * I_DIM + f0 + lm;
#pragma unroll
            for (int nf = 0; nf < 4; ++nf) {
                float up = acc[mi][nf][rr];
                float gt = acc[mi][nf + 4][rr];
                float v  = up * gt / (1.f + expf(-gt));
                orow[nf * 16] = f2bf(v);
            }
        }
    }
}

// ---------------- grouped MFMA GEMM2 (dense slots -> scatter out) ----------
__global__ __launch_bounds__(256) void gemm2_mfma_kernel(
    const short* __restrict__ actm, const short* __restrict__ w2t,
    const int* __restrict__ offP, const int* __restrict__ slot_tok,
    float* __restrict__ out)
{
    __shared__ short sA[2][128 * 32];
    __shared__ short sB[2][128 * 32];
    __shared__ int   sTok[128];

    const int bid = blockIdx.x;
    const int wg  = (bid & 7) * 80 + (bid >> 3);
    const int nt  = wg / MT;
    const int mt  = wg - nt * MT;
    const int m0  = mt << 7;
    if (m0 >= offP[E_NUM]) return;
    const int h0  = nt << 7;

    int e = 0;
#pragma unroll
    for (int k = 1; k < E_NUM; ++k) if (m0 >= offP[k]) e = k;

    const int tid = threadIdx.x, lane = tid & 63, w = tid >> 6;
    if (tid < 128) sTok[tid] = slot_tok[m0 + tid];

    const int g = lane & 3, lr = lane >> 2;
    const int rA0 = (2 * w) * 16 + lr, rA1 = rA0 + 16;

    const short* srcA0 = actm + (size_t)(m0 + rA0) * I_DIM + g * 8;
    const short* srcA1 = actm + (size_t)(m0 + rA1) * I_DIM + g * 8;
    const short* srcB0 = w2t + ((size_t)e * H_DIM + h0 + rA0) * I_DIM + g * 8;
    const short* srcB1 = w2t + ((size_t)e * H_DIM + h0 + rA1) * I_DIM + g * 8;

    const int lm = lane & 15, lg8 = (lane >> 4) * 8;
    const int offA = (w * 32 + lm) * 32 + lg8;
    const int offB = lm * 32 + lg8;

    f32x4 acc[2][8];
#pragma unroll
    for (int i = 0; i < 2; ++i)
#pragma unroll
        for (int j = 0; j < 8; ++j) acc[i][j] = (f32x4){0.f, 0.f, 0.f, 0.f};

    auto STG = [&](int buf, int kb) {
        gload16(srcA0 + kb, &sA[buf][(2 * w) * 512]);
        gload16(srcA1 + kb, &sA[buf][(2 * w + 1) * 512]);
        gload16(srcB0 + kb, &sB[buf][(2 * w) * 512]);
        gload16(srcB1 + kb, &sB[buf][(2 * w + 1) * 512]);
    };
    auto CMP = [&](int buf) {
        const short* pA = &sA[buf][offA];
        const short* pB = &sB[buf][offB];
        bf16x8 a0 = *(const bf16x8*)pA;
        bf16x8 a1 = *(const bf16x8*)(pA + 512);
#pragma unroll
        for (int nf = 0; nf < 8; ++nf) {
            bf16x8 b = *(const bf16x8*)(pB + nf * 512);
            acc[0][nf] = __builtin_amdgcn_mfma_f32_16x16x32_bf16(a0, b, acc[0][nf], 0, 0, 0);
            acc[1][nf] = __builtin_amdgcn_mfma_f32_16x16x32_bf16(a1, b, acc[1][nf], 0, 0, 0);
        }
    };

    int cur = 0;
    STG(0, 0);
    for (int kb = 32; kb < I_DIM; kb += 32) {
        __syncthreads();
        STG(cur ^ 1, kb);
        CMP(cur);
        cur ^= 1;
    }
    __syncthreads();
    CMP(cur);

    const int rbase = w * 32 + (lane >> 4) * 4;
#pragma unroll
    for (int mi = 0; mi < 2; ++mi) {
#pragma unroll
        for (int rr = 0; rr < 4; ++rr) {
            const int row = rbase + mi * 16 + rr;
            const int tok = sTok[row];
            if (tok < 0) continue;
            float* orow = out + (size_t)tok * H_DIM + h0 + lm;
#pragma unroll
            for (int nf = 0; nf < 8; ++nf) orow[nf * 16] = acc[mi][nf][rr];
        }
    }
}

extern "C" void kernel_launch(void* const* d_in, const int* in_sizes, int n_in,
                              void* d_out, int out_size, void* d_ws, size_t ws_size,
                              hipStream_t stream) {
    const float* x   = (const float*)d_in[0];
    const float* gw  = (const float*)d_in[1];
    const float* gup = (const float*)d_in[2];
    const float* dw  = (const float*)d_in[3];
    float* out = (float*)d_out;

    char* ws = (char*)d_ws;
    float* scale    = (float*)(ws + WS_SCALE);
    int*   counts   = (int*)(ws + WS_COUNTS);
    int*   offP     = (int*)(ws + WS_OFFP);
    int*   buckets  = (int*)(ws + WS_BUCKETS);
    int*   slot_tok = (int*)(ws + WS_SLOTTOK);
    short* xsg      = (short*)(ws + WS_XSG);
    short* act      = (short*)(ws + WS_ACT);
    short* w1t      = (short*)(ws + WS_W1T);
    short* w2t      = (short*)(ws + WS_W2T);

    hipMemsetAsync(counts, 0, E_NUM * sizeof(int), stream);

    // router + both weight transposes, fused & concurrent (independent work)
    prep_kernel<<<1024 + 8192 + 4096, 256, 0, stream>>>(
        x, gw, gup, dw, scale, counts, buckets, w1t, w2t);

    offs_kernel<<<1, 64, 0, stream>>>(counts, offP);
    gather_kernel<<<MROWS, 256, 0, stream>>>(x, scale, counts, offP, buckets, xsg, slot_tok);

    gemm1_mfma_kernel<<<MT * 16, 256, 0, stream>>>(xsg, w1t, offP, act);
    gemm2_mfma_kernel<<<MT * 16, 256, 0, stream>>>(act, w2t, offP, slot_tok, out);
}